// Round 1
// 1447.697 us; speedup vs baseline: 1.1326x; 1.1326x over previous
//
#include <hip/hip_runtime.h>
#include <hip/hip_bf16.h>
#include <math.h>

#define BB   8
#define CC   256
#define HH   128
#define WW   128
#define MID  64
#define NPIX (HH * WW)          // 16384
#define BN_EPS 1e-5f

// LDS staging pitch/rows for 32x32-output-tile rotation kernels.
// Max input bbox span for a 31-px tile under any rotation: 31*sqrt(2)+3 < 48.
#define TPITCH 56
#define TROWS  56

// Table geometry: 4 angles x 2 dirs x 16 tiles x 1024 pixels
#define NTBL (4 * 2 * 16 * 1024)

__device__ __forceinline__ void rot_coords(int xx, int yy, float c, float s,
                                           int& x0, int& y0, float& wx1, float& wy1) {
    float X = -1.0f + (2.0f * (float)xx) / (float)(WW - 1);
    float Y = -1.0f + (2.0f * (float)yy) / (float)(HH - 1);
    float gx = c * X - s * Y;
    float gy = s * X + c * Y;
    float ix = (gx + 1.0f) * 0.5f * (float)(WW - 1);
    float iy = (gy + 1.0f) * 0.5f * (float)(HH - 1);
    float fx = floorf(ix), fy = floorf(iy);
    x0 = (int)fx; y0 = (int)fy;
    wx1 = ix - fx; wy1 = iy - fy;
}

__device__ __forceinline__ void rot_ixiy(float xx, float yy, float c, float s,
                                         float& ix, float& iy) {
    float X = -1.0f + (2.0f * xx) / (float)(WW - 1);
    float Y = -1.0f + (2.0f * yy) / (float)(HH - 1);
    float gx = c * X - s * Y;
    float gy = s * X + c * Y;
    ix = (gx + 1.0f) * 0.5f * (float)(WW - 1);
    iy = (gy + 1.0f) * 0.5f * (float)(HH - 1);
}

// Compute input-space bbox for a 32x32 output tile under rotation (c,s).
__device__ __forceinline__ void tile_bbox(int tx, int ty, float c, float s,
                                          int& x_lo, int& y_lo, int& bw, int& bh) {
    float ix00, iy00, ix10, iy10, ix01, iy01, ix11, iy11;
    rot_ixiy((float)tx,        (float)ty,        c, s, ix00, iy00);
    rot_ixiy((float)(tx + 31), (float)ty,        c, s, ix10, iy10);
    rot_ixiy((float)tx,        (float)(ty + 31), c, s, ix01, iy01);
    rot_ixiy((float)(tx + 31), (float)(ty + 31), c, s, ix11, iy11);
    float minix = fminf(fminf(ix00, ix10), fminf(ix01, ix11));
    float maxix = fmaxf(fmaxf(ix00, ix10), fmaxf(ix01, ix11));
    float miniy = fminf(fminf(iy00, iy10), fminf(iy01, iy11));
    float maxiy = fmaxf(fmaxf(iy00, iy10), fmaxf(iy01, iy11));
    x_lo = max((int)floorf(minix) - 1, 0);
    int x_hi = min((int)floorf(maxix) + 2, WW - 1);
    y_lo = max((int)floorf(miniy) - 1, 0);
    int y_hi = min((int)floorf(maxiy) + 2, HH - 1);
    x_hi = max(x_hi, x_lo);
    y_hi = max(y_hi, y_lo);
    bw = x_hi - x_lo + 1;   // <= 48
    bh = y_hi - y_lo + 1;
}

// Kernel 0 (once): precompute bilinear weights + clamped LDS offsets + bboxes
// for every (angle, dir, tile, pixel). Geometry is plane-independent, so this
// removes ~75 VALU ops/pixel from the 2048-plane rotate/invrot kernels.
__global__ void k_tables(const float* __restrict__ angles, float4* __restrict__ wtab,
                         ushort4* __restrict__ otab, int4* __restrict__ btab) {
    int blk  = blockIdx.x;            // (ai*2 + dir)*16 + tile, 128 blocks
    int tile = blk & 15;
    int dir  = (blk >> 4) & 1;
    int ai   = blk >> 5;
    float ang = angles[ai];
    float c = cosf(ang);
    float s = dir ? -sinf(ang) : sinf(ang);
    int ty = (tile >> 2) << 5;
    int tx = (tile & 3) << 5;

    int x_lo, y_lo, bw, bh;
    tile_bbox(tx, ty, c, s, x_lo, y_lo, bw, bh);

    for (int k = 0; k < 4; ++k) {
        int p = threadIdx.x + (k << 8);
        int yy = ty + (p >> 5);
        int xx = tx + (p & 31);
        int x0, y0; float wx1, wy1;
        rot_coords(xx, yy, c, s, x0, y0, wx1, wy1);
        int x1 = x0 + 1, y1 = y0 + 1;
        float wx0 = 1.f - wx1, wy0 = 1.f - wy1;
        bool vx0 = (unsigned)x0 < WW, vx1 = (unsigned)x1 < WW;
        bool vy0 = (unsigned)y0 < HH, vy1 = (unsigned)y1 < HH;
        float w00 = (vx0 && vy0) ? wx0 * wy0 : 0.f;
        float w10 = (vx1 && vy0) ? wx1 * wy0 : 0.f;
        float w01 = (vx0 && vy1) ? wx0 * wy1 : 0.f;
        float w11 = (vx1 && vy1) ? wx1 * wy1 : 0.f;
        int lx0 = min(max(x0 - x_lo, 0), bw - 1);
        int lx1 = min(max(x1 - x_lo, 0), bw - 1);
        int ly0 = min(max(y0 - y_lo, 0), bh - 1);
        int ly1 = min(max(y1 - y_lo, 0), bh - 1);
        int e = (blk << 10) + p;
        wtab[e] = make_float4(w00, w10, w01, w11);
        otab[e] = make_ushort4((unsigned short)(ly0 * TPITCH + lx0),
                               (unsigned short)(ly0 * TPITCH + lx1),
                               (unsigned short)(ly1 * TPITCH + lx0),
                               (unsigned short)(ly1 * TPITCH + lx1));
    }
    if (threadIdx.x == 0) btab[blk] = make_int4(x_lo, y_lo, bw, bh);
}

// Kernel 1 (tiled, table-driven): rotate x by +angle into bf16 xr; per-tile
// partial sum -> p_part. One block per (plane, 32x32 tile).
__global__ void k_rotate(const float* __restrict__ x, const float4* __restrict__ wtab,
                         const ushort4* __restrict__ otab, const int4* __restrict__ btab,
                         int ai, __hip_bfloat16* __restrict__ xr, float* __restrict__ p_part) {
    __shared__ float lds[TROWS * TPITCH];
    __shared__ float red[4];

    int plane = blockIdx.x >> 4;
    int tile  = blockIdx.x & 15;
    int ty = (tile >> 2) << 5;
    int tx = (tile & 3) << 5;
    int tb = (ai << 5) + tile;           // dir = 0

    int4 bb = btab[tb];                  // x_lo, y_lo, bw, bh
    const float* img = x + (size_t)plane * NPIX;
    __hip_bfloat16* op = xr + (size_t)plane * NPIX;

    int srow = threadIdx.x >> 6;
    int scol = threadIdx.x & 63;
    for (int r = srow; r < bb.w; r += 4) {
        if (scol < bb.z)
            lds[r * TPITCH + scol] = img[(bb.y + r) * WW + (bb.x + scol)];
    }
    __syncthreads();

    const float4*  wt = wtab + ((size_t)tb << 10);
    const ushort4* ot = otab + ((size_t)tb << 10);
    float lsum = 0.0f;
    for (int k = 0; k < 4; ++k) {
        int p = threadIdx.x + (k << 8);
        float4  w = wt[p];
        ushort4 o = ot[p];
        float v = w.x * lds[o.x] + w.y * lds[o.y]
                + w.z * lds[o.z] + w.w * lds[o.w];
        int yy = ty + (p >> 5);
        int xx = tx + (p & 31);
        op[yy * WW + xx] = __float2bfloat16(v);
        lsum += v;
    }
    for (int off = 32; off > 0; off >>= 1) lsum += __shfl_down(lsum, off, 64);
    if ((threadIdx.x & 63) == 0) red[threadIdx.x >> 6] = lsum;
    __syncthreads();
    if (threadIdx.x == 0)
        p_part[blockIdx.x] = red[0] + red[1] + red[2] + red[3];
}

// Kernel 2: reduce p_part, tiny MLP. One block per batch (8 blocks).
__global__ void k_mlp(const float* __restrict__ p_part, const float* __restrict__ w1,
                      const float* __restrict__ g, const float* __restrict__ be,
                      const float* __restrict__ mu, const float* __restrict__ var,
                      const float* __restrict__ w2, float* __restrict__ ca) {
    __shared__ float sp[CC];
    __shared__ float sh[MID];
    int b = blockIdx.x;
    int t = threadIdx.x;

    // p[b][t] = mean over pixels = sum of 16 tile partials / NPIX
    const float* pr = p_part + (size_t)(b * CC + t) * 16;
    float acc = 0.f;
    for (int k = 0; k < 16; ++k) acc += pr[k];
    sp[t] = acc * (1.0f / (float)NPIX);
    __syncthreads();

    // h[m] = relu(BN(p . w1[m])): 64 outputs x 4 thread-quarters of 64 MACs
    int m = t >> 2, q = t & 3;
    const float* w1r = w1 + m * CC + (q << 6);
    const float* spq = sp + (q << 6);
    float a = 0.f;
    for (int k = 0; k < 64; ++k) a += spq[k] * w1r[k];
    a += __shfl_xor(a, 1, 64);
    a += __shfl_xor(a, 2, 64);
    if (q == 0) {
        a = (a - mu[m]) * rsqrtf(var[m] + BN_EPS) * g[m] + be[m];
        sh[m] = fmaxf(a, 0.f);
    }
    __syncthreads();

    // ca[ch] = sigmoid(h . w2[ch]): one channel per thread
    const float* w2r = w2 + t * MID;
    float a2 = 0.f;
    for (int k = 0; k < MID; ++k) a2 += sh[k] * w2r[k];
    ca[b * CC + t] = 1.f / (1.f + expf(-a2));
}

// Kernel 3: per-pixel channel avg & max of fca = xr * ca.
// 4-way channel split per block for 4x the blocks/occupancy of the old version.
__global__ void k_chanstat(const __hip_bfloat16* __restrict__ xr, const float* __restrict__ ca,
                           float* __restrict__ avg, float* __restrict__ mx) {
    __shared__ float rs0[4][64], rs1[4][64], rm0[4][64], rm1[4][64];
    int b    = blockIdx.x >> 7;
    int grp  = blockIdx.x & 127;            // 128 groups of 64 pixel-pairs
    int lane = threadIdx.x & 63;
    int cg   = threadIdx.x >> 6;            // channel group 0..3
    int pp   = (grp << 6) + lane;           // pixel-pair index 0..8191

    const unsigned* xp = (const unsigned*)(xr + (size_t)b * CC * NPIX) + pp
                       + (size_t)(cg << 6) * (NPIX / 2);
    const float* cab = ca + b * CC + (cg << 6);

    float s0 = 0.f, s1 = 0.f, m0 = -INFINITY, m1 = -INFINITY;
    for (int ch = 0; ch < 64; ++ch) {
        unsigned u = xp[(size_t)ch * (NPIX / 2)];
        float v0 = __uint_as_float(u << 16);
        float v1 = __uint_as_float(u & 0xffff0000u);
        float cc = cab[ch];
        v0 *= cc; v1 *= cc;
        s0 += v0; s1 += v1;
        m0 = fmaxf(m0, v0); m1 = fmaxf(m1, v1);
    }
    rs0[cg][lane] = s0; rs1[cg][lane] = s1;
    rm0[cg][lane] = m0; rm1[cg][lane] = m1;
    __syncthreads();
    if (threadIdx.x < 64) {
        int l = threadIdx.x;
        float a0 = rs0[0][l] + rs0[1][l] + rs0[2][l] + rs0[3][l];
        float a1 = rs1[0][l] + rs1[1][l] + rs1[2][l] + rs1[3][l];
        float b0 = fmaxf(fmaxf(rm0[0][l], rm0[1][l]), fmaxf(rm0[2][l], rm0[3][l]));
        float b1 = fmaxf(fmaxf(rm1[0][l], rm1[1][l]), fmaxf(rm1[2][l], rm1[3][l]));
        float2* ap = (float2*)(avg + b * NPIX);
        float2* mp = (float2*)(mx + b * NPIX);
        int o = (grp << 6) + l;
        ap[o] = make_float2(a0 * (1.0f / (float)CC), a1 * (1.0f / (float)CC));
        mp[o] = make_float2(b0, b1);
    }
}

// Kernel 4: 7x7 conv (2 in-ch -> 1), pad 3, sigmoid -> sa.
__global__ void k_conv(const float* __restrict__ avg, const float* __restrict__ mx,
                       const float* __restrict__ w_sp, float* __restrict__ sa) {
    __shared__ float w[98];
    int t = threadIdx.x;
    if (t < 98) w[t] = w_sp[t];
    __syncthreads();
    int b = blockIdx.x >> 6;
    int pix = ((blockIdx.x & 63) << 8) + t;
    int yy = pix >> 7, xx = pix & (WW - 1);
    const float* a0 = avg + b * NPIX;
    const float* a1 = mx + b * NPIX;
    float acc = 0.f;
    for (int ky = 0; ky < 7; ++ky) {
        int ys = yy + ky - 3;
        if ((unsigned)ys >= HH) continue;
        for (int kx = 0; kx < 7; ++kx) {
            int xs = xx + kx - 3;
            if ((unsigned)xs >= WW) continue;
            acc += a0[ys * WW + xs] * w[ky * 7 + kx] + a1[ys * WW + xs] * w[49 + ky * 7 + kx];
        }
    }
    sa[b * NPIX + pix] = 1.f / (1.f + expf(-acc));
}

// Kernel 5 (tiled, table-driven): inverse rotate fatt = xr*ca*sa, scale 1/4, accumulate.
__global__ void k_invrot(const __hip_bfloat16* __restrict__ xr, const float* __restrict__ ca,
                         const float* __restrict__ sa, const float4* __restrict__ wtab,
                         const ushort4* __restrict__ otab, const int4* __restrict__ btab,
                         int ai, int first, float* __restrict__ out) {
    __shared__ float lds[TROWS * TPITCH];

    int plane = blockIdx.x >> 4;
    int tile  = blockIdx.x & 15;
    int b = plane >> 8;
    int ty = (tile >> 2) << 5;
    int tx = (tile & 3) << 5;
    int tb = (ai << 5) + 16 + tile;      // dir = 1

    int4 bb = btab[tb];
    float scale = ca[plane] * 0.25f;

    const __hip_bfloat16* xp = xr + (size_t)plane * NPIX;
    const float* sp = sa + b * NPIX;
    float* op = out + (size_t)plane * NPIX;

    int srow = threadIdx.x >> 6;
    int scol = threadIdx.x & 63;
    for (int r = srow; r < bb.w; r += 4) {
        if (scol < bb.z) {
            int gidx = (bb.y + r) * WW + (bb.x + scol);
            lds[r * TPITCH + scol] = __bfloat162float(xp[gidx]) * sp[gidx];
        }
    }
    __syncthreads();

    const float4*  wt = wtab + ((size_t)tb << 10);
    const ushort4* ot = otab + ((size_t)tb << 10);
    for (int k = 0; k < 4; ++k) {
        int p = threadIdx.x + (k << 8);
        float4  w = wt[p];
        ushort4 o = ot[p];
        float v = w.x * lds[o.x] + w.y * lds[o.y]
                + w.z * lds[o.z] + w.w * lds[o.w];
        int yy = ty + (p >> 5);
        int xx = tx + (p & 31);
        float ov = v * scale;
        int oi = yy * WW + xx;
        if (first) op[oi] = ov;
        else       op[oi] += ov;
    }
}

extern "C" void kernel_launch(void* const* d_in, const int* in_sizes, int n_in,
                              void* d_out, int out_size, void* d_ws, size_t ws_size,
                              hipStream_t stream) {
    const float* x      = (const float*)d_in[0];
    const float* angles = (const float*)d_in[1];
    const float* w1     = (const float*)d_in[2];
    const float* gmm    = (const float*)d_in[3];
    const float* bet    = (const float*)d_in[4];
    const float* mu     = (const float*)d_in[5];
    const float* var    = (const float*)d_in[6];
    const float* w2     = (const float*)d_in[7];
    const float* wsp    = (const float*)d_in[8];
    float* out = (float*)d_out;

    char* ws = (char*)d_ws;
    __hip_bfloat16* xr = (__hip_bfloat16*)ws;                   // 64 MiB
    float* p_part = (float*)(ws + (size_t)BB * CC * NPIX * 2);  // 2048*16 floats
    float* ca  = p_part + BB * CC * 16;
    float* avg = ca + BB * CC;
    float* mx  = avg + BB * NPIX;
    float* sa  = mx + BB * NPIX;
    float4*  wtab = (float4*)(sa + BB * NPIX);                  // 2 MiB (16B-aligned)
    ushort4* otab = (ushort4*)(wtab + NTBL);                    // 1 MiB
    int4*    btab = (int4*)(otab + NTBL);                       // 2 KiB

    k_tables<<<128, 256, 0, stream>>>(angles, wtab, otab, btab);

    for (int ai = 0; ai < 4; ++ai) {
        k_rotate  <<<BB * CC * 16, 256, 0, stream>>>(x, wtab, otab, btab, ai, xr, p_part);
        k_mlp     <<<BB, 256, 0, stream>>>(p_part, w1, gmm, bet, mu, var, w2, ca);
        k_chanstat<<<BB * 128, 256, 0, stream>>>(xr, ca, avg, mx);
        k_conv    <<<BB * 64, 256, 0, stream>>>(avg, mx, wsp, sa);
        k_invrot  <<<BB * CC * 16, 256, 0, stream>>>(xr, ca, sa, wtab, otab, btab, ai, ai == 0, out);
    }
}